// Round 1
// baseline (4772.387 us; speedup 1.0000x reference)
//
#include <hip/hip_runtime.h>

// SolarRNN: B=256, T=4096, F=16, H=64. Two fused GRU layers + online-softmax
// attention + MLP tail, all in ONE persistent kernel: block b = sequence b.
// 4 waves/block (one per SIMD), K-split-4 with LDS reduction, fp32 throughout.

#define B_ 256
#define T_ 4096
#define F_ 16
#define H_ 64
#define L2E 1.4426950408889634f

__device__ __forceinline__ float rdlane(float v, int lane) {
    return __builtin_bit_cast(float, __builtin_amdgcn_readlane(__builtin_bit_cast(int, v), lane));
}
__device__ __forceinline__ float sigm(float x) {
    float e = __builtin_amdgcn_exp2f(-L2E * x);
    return __builtin_amdgcn_rcpf(1.0f + e);
}
__device__ __forceinline__ float tanh_(float x) {
    float e = __builtin_amdgcn_exp2f(2.0f * L2E * x);
    return 1.0f - 2.0f * __builtin_amdgcn_rcpf(1.0f + e);
}

__launch_bounds__(256, 1)
__global__ void solar_rnn(const float* __restrict__ x,
                          const float* __restrict__ Wi1, const float* __restrict__ bi1,
                          const float* __restrict__ Whr1, const float* __restrict__ Whz1,
                          const float* __restrict__ Whn1, const float* __restrict__ bhn1,
                          const float* __restrict__ Wi2, const float* __restrict__ bi2,
                          const float* __restrict__ Whr2, const float* __restrict__ Whz2,
                          const float* __restrict__ Whn2, const float* __restrict__ bhn2,
                          const float* __restrict__ Wp, const float* __restrict__ bp,
                          const float* __restrict__ Wa,
                          const float* __restrict__ W1, const float* __restrict__ b1,
                          const float* __restrict__ W2, const float* __restrict__ b2,
                          const float* __restrict__ W3, const float* __restrict__ b3,
                          const float* __restrict__ W4, const float* __restrict__ b4,
                          float* __restrict__ out)
{
    const int b   = blockIdx.x;
    const int tid = threadIdx.x;
    const int w   = tid >> 6;   // wave 0..3 (one per SIMD)
    const int j   = tid & 63;   // lane = output index

    // conflict-free reduction buffers: [acc][wave][j] -> lane j is stride-1
    __shared__ float redL1[5][4][H_];   // r, z, in, hn, xp
    __shared__ float redL2[4][4][H_];   // r, z, in, hn
    __shared__ float sm_a[128];
    __shared__ float sm_b[128];

    // ---- per-lane weight slices (wave w owns K-rows [16w,16w+16)) ----
    float wr1[16], wz1[16], wn1[16];        // layer-1 hidden kernels, col j
    float wr2[16], wz2[16], wn2[16];        // layer-2 hidden kernels, col j
    float w2r[16], w2z[16], w2n[16];        // Wi2 (o1 -> gates), col j
    #pragma unroll
    for (int k = 0; k < 16; ++k) {
        const int row = 16 * w + k;
        wr1[k] = Whr1[row * H_ + j];
        wz1[k] = Whz1[row * H_ + j];
        wn1[k] = Whn1[row * H_ + j];
        wr2[k] = Whr2[row * H_ + j];
        wz2[k] = Whz2[row * H_ + j];
        wn2[k] = Whn2[row * H_ + j];
        w2r[k] = Wi2[row * 192 + j];
        w2z[k] = Wi2[row * 192 + 64 + j];
        w2n[k] = Wi2[row * 192 + 128 + j];
    }
    float w1r[4], w1z[4], w1n[4], wpv[4];   // Wi1 / Wp (K=16 -> 4 rows per wave)
    #pragma unroll
    for (int k = 0; k < 4; ++k) {
        const int row = 4 * w + k;
        w1r[k] = Wi1[row * 192 + j];
        w1z[k] = Wi1[row * 192 + 64 + j];
        w1n[k] = Wi1[row * 192 + 128 + j];
        wpv[k] = Wp[row * H_ + j];
    }
    const float bi1r = bi1[j], bi1z = bi1[64 + j], bi1n = bi1[128 + j], bh1 = bhn1[j];
    const float bi2r = bi2[j], bi2z = bi2[64 + j], bi2n = bi2[128 + j], bh2 = bhn2[j];
    const float bpj  = bp[j],  waj  = Wa[j];
    // ba is a constant shift on pre-softmax scores -> softmax-invariant, skipped.

    float h1 = 0.f, h2 = 0.f;               // lane j holds h[j], replicated per wave
    float sH1[16], sH2[16];                 // wave-uniform h-slice (via readlane)
    #pragma unroll
    for (int k = 0; k < 16; ++k) { sH1[k] = 0.f; sH2[k] = 0.f; }

    // online-softmax attention state (per lane j; s is wave-uniform)
    float am = -3.0e38f, al = 0.f, aa = 0.f;

    const float* xb = x + (size_t)b * T_ * F_;

    #pragma unroll 1
    for (int tc = 0; tc < T_ / 64; ++tc) {
        // 64 steps of x per wave: lane l holds x[tc*64+l][4w..4w+4)
        const float4 xq = *(const float4*)(xb + ((tc * 64 + j) * F_ + 4 * w));
        #pragma unroll 1
        for (int ti = 0; ti < 64; ++ti) {
            const float x0 = rdlane(xq.x, ti);
            const float x1 = rdlane(xq.y, ti);
            const float x2 = rdlane(xq.z, ti);
            const float x3 = rdlane(xq.w, ti);

            // ---- L2 hidden-part partials (independent of this step's L1) ----
            float ar2 = 0.f, az2 = 0.f, ahn2 = 0.f;
            #pragma unroll
            for (int k = 0; k < 16; ++k) {
                ar2  = fmaf(sH2[k], wr2[k], ar2);
                az2  = fmaf(sH2[k], wz2[k], az2);
                ahn2 = fmaf(sH2[k], wn2[k], ahn2);
            }

            // ---- L1 partials: recurrent + input projection + x_proj ----
            float ar = 0.f, az = 0.f, ahn = 0.f;
            #pragma unroll
            for (int k = 0; k < 16; ++k) {
                ar  = fmaf(sH1[k], wr1[k], ar);
                az  = fmaf(sH1[k], wz1[k], az);
                ahn = fmaf(sH1[k], wn1[k], ahn);
            }
            float ain = fmaf(x0, w1n[0], fmaf(x1, w1n[1], fmaf(x2, w1n[2], x3 * w1n[3])));
            float axp = fmaf(x0, wpv[0], fmaf(x1, wpv[1], fmaf(x2, wpv[2], x3 * wpv[3])));
            ar = fmaf(x0, w1r[0], ar); ar = fmaf(x1, w1r[1], ar);
            ar = fmaf(x2, w1r[2], ar); ar = fmaf(x3, w1r[3], ar);
            az = fmaf(x0, w1z[0], az); az = fmaf(x1, w1z[1], az);
            az = fmaf(x2, w1z[2], az); az = fmaf(x3, w1z[3], az);

            redL1[0][w][j] = ar;  redL1[1][w][j] = az;  redL1[2][w][j] = ain;
            redL1[3][w][j] = ahn; redL1[4][w][j] = axp;
            __syncthreads();

            // ---- L1 reduce + pointwise (redundant on all waves, identical) ----
            const float pr  = (redL1[0][0][j] + redL1[0][1][j]) + (redL1[0][2][j] + redL1[0][3][j]);
            const float pz  = (redL1[1][0][j] + redL1[1][1][j]) + (redL1[1][2][j] + redL1[1][3][j]);
            const float pin = (redL1[2][0][j] + redL1[2][1][j]) + (redL1[2][2][j] + redL1[2][3][j]);
            const float phn = (redL1[3][0][j] + redL1[3][1][j]) + (redL1[3][2][j] + redL1[3][3][j]);
            const float pxp = (redL1[4][0][j] + redL1[4][1][j]) + (redL1[4][2][j] + redL1[4][3][j]);
            const float r1 = sigm(pr + bi1r);
            const float z1 = sigm(pz + bi1z);
            const float n1 = tanh_((pin + bi1n) + r1 * (phn + bh1));
            h1 = n1 + z1 * (h1 - n1);                 // (1-z)n + z h
            const float o1 = h1 + 0.5f * (pxp + bpj); // residual x-projection

            // broadcast h1/o1 slices as wave-uniform scalars
            float sO1[16];
            #pragma unroll
            for (int k = 0; k < 16; ++k) {
                sH1[k] = rdlane(h1, 16 * w + k);
                sO1[k] = rdlane(o1, 16 * w + k);
            }
            // ---- L2 input-projection partials (o1 @ Wi2) ----
            float ain2 = 0.f;
            #pragma unroll
            for (int k = 0; k < 16; ++k) {
                ar2  = fmaf(sO1[k], w2r[k], ar2);
                az2  = fmaf(sO1[k], w2z[k], az2);
                ain2 = fmaf(sO1[k], w2n[k], ain2);
            }
            redL2[0][w][j] = ar2; redL2[1][w][j] = az2;
            redL2[2][w][j] = ain2; redL2[3][w][j] = ahn2;
            __syncthreads();

            // ---- L2 reduce + pointwise ----
            const float qr  = (redL2[0][0][j] + redL2[0][1][j]) + (redL2[0][2][j] + redL2[0][3][j]);
            const float qz  = (redL2[1][0][j] + redL2[1][1][j]) + (redL2[1][2][j] + redL2[1][3][j]);
            const float qin = (redL2[2][0][j] + redL2[2][1][j]) + (redL2[2][2][j] + redL2[2][3][j]);
            const float qhn = (redL2[3][0][j] + redL2[3][1][j]) + (redL2[3][2][j] + redL2[3][3][j]);
            const float r2 = sigm(qr + bi2r);
            const float z2 = sigm(qz + bi2z);
            const float n2 = tanh_((qin + bi2n) + r2 * (qhn + bh2));
            h2 = n2 + z2 * (h2 - n2);
            const float o2 = h2 + 0.5f * o1;
            #pragma unroll
            for (int k = 0; k < 16; ++k) sH2[k] = rdlane(h2, 16 * w + k);

            // ---- online-softmax attention: s = <o2, Wa> (wave-uniform) ----
            float p = o2 * waj;
            #pragma unroll
            for (int mask = 32; mask >= 1; mask >>= 1) p += __shfl_xor(p, mask);
            const float mn = fmaxf(am, p);
            const float ca = __builtin_amdgcn_exp2f((am - mn) * L2E);
            const float ce = __builtin_amdgcn_exp2f((p  - mn) * L2E);
            al = fmaf(al, ca, ce);
            aa = fmaf(aa, ca, ce * o2);
            am = mn;
        }
    }

    // ---- attended vector + MLP tail (once per block) ----
    const float att = aa / al;
    if (tid < 64) sm_a[tid] = att;          // wave-0 copy (replicated across waves)
    __syncthreads();

    float v1 = 0.f;
    if (tid < 128) {
        float a = b1[tid];
        for (int k = 0; k < 64; ++k) a = fmaf(sm_a[k], W1[k * 128 + tid], a);
        v1 = fmaxf(a, 0.f);
    }
    __syncthreads();
    if (tid < 128) sm_b[tid] = v1;
    __syncthreads();
    if (tid < 64) {
        float a = b2[tid];
        for (int k = 0; k < 128; ++k) a = fmaf(sm_b[k], W2[k * 64 + tid], a);
        sm_a[tid] = fmaxf(a, 0.f);
    }
    __syncthreads();
    if (tid < 32) {
        float a = b3[tid];
        for (int k = 0; k < 64; ++k) a = fmaf(sm_a[k], W3[k * 32 + tid], a);
        sm_b[tid] = fmaxf(a, 0.f);
    }
    __syncthreads();
    if (tid < 2) {
        float a = b4[tid];
        for (int k = 0; k < 32; ++k) a = fmaf(sm_b[k], W4[k * 2 + tid], a);
        out[b * 2 + tid] = a;
    }
}

extern "C" void kernel_launch(void* const* d_in, const int* in_sizes, int n_in,
                              void* d_out, int out_size, void* d_ws, size_t ws_size,
                              hipStream_t stream) {
    const float* x    = (const float*)d_in[0];
    const float* Wi1  = (const float*)d_in[1];
    const float* bi1  = (const float*)d_in[2];
    const float* Whr1 = (const float*)d_in[3];
    const float* Whz1 = (const float*)d_in[4];
    const float* Whn1 = (const float*)d_in[5];
    const float* bhn1 = (const float*)d_in[6];
    const float* Wi2  = (const float*)d_in[7];
    const float* bi2  = (const float*)d_in[8];
    const float* Whr2 = (const float*)d_in[9];
    const float* Whz2 = (const float*)d_in[10];
    const float* Whn2 = (const float*)d_in[11];
    const float* bhn2 = (const float*)d_in[12];
    const float* Wp   = (const float*)d_in[13];
    const float* bp   = (const float*)d_in[14];
    const float* Wa   = (const float*)d_in[15];
    // d_in[16] = ba: softmax shift-invariant, unused
    const float* W1   = (const float*)d_in[17];
    const float* b1   = (const float*)d_in[18];
    const float* W2   = (const float*)d_in[19];
    const float* b2   = (const float*)d_in[20];
    const float* W3   = (const float*)d_in[21];
    const float* b3   = (const float*)d_in[22];
    const float* W4   = (const float*)d_in[23];
    const float* b4   = (const float*)d_in[24];

    solar_rnn<<<dim3(B_), dim3(256), 0, stream>>>(
        x, Wi1, bi1, Whr1, Whz1, Whn1, bhn1,
        Wi2, bi2, Whr2, Whz2, Whn2, bhn2,
        Wp, bp, Wa, W1, b1, W2, b2, W3, b3, W4, b4,
        (float*)d_out);
}